// Round 12
// baseline (224.576 us; speedup 1.0000x reference)
//
#include <hip/hip_runtime.h>

#define N_NODES 100000
#define N_EDGES 3200000
#define IN_CH 512
#define HID 16
#define OUT_CH 64

// ---- single-level counting-sort geometry ----
// 391 buckets x 256 nodes (bucket = dst>>8). Count mean 8192, sigma 90.4;
// BCAP = mean + 14sigma -> overflow prob ~1e-40.
#define NB 391
#define BCAP 9472
#define BIN1_CHUNK 4096
#define BIN1_BLOCKS ((N_EDGES + BIN1_CHUNK - 1) / BIN1_CHUNK)  // 782

typedef float f4 __attribute__((ext_vector_type(4)));
typedef unsigned int v2u __attribute__((ext_vector_type(2)));
typedef unsigned int v4u __attribute__((ext_vector_type(4)));

// bf16 pack/unpack (RNE)
__device__ __forceinline__ unsigned rne(float f) {
    unsigned u = __float_as_uint(f);
    return (u + 0x7fffu + ((u >> 16) & 1u)) >> 16;
}
__device__ __forceinline__ v2u pk4(f4 f) {
    v2u r;
    r.x = rne(f.x) | (rne(f.y) << 16);
    r.y = rne(f.z) | (rne(f.w) << 16);
    return r;
}
__device__ __forceinline__ f4 up_lo(v4u v) {   // channels 0..3 of the 8
    f4 r;
    r.x = __uint_as_float(v.x << 16);
    r.y = __uint_as_float(v.x & 0xffff0000u);
    r.z = __uint_as_float(v.y << 16);
    r.w = __uint_as_float(v.y & 0xffff0000u);
    return r;
}
__device__ __forceinline__ f4 up_hi(v4u v) {   // channels 4..7
    f4 r;
    r.x = __uint_as_float(v.z << 16);
    r.y = __uint_as_float(v.z & 0xffff0000u);
    r.z = __uint_as_float(v.w << 16);
    r.w = __uint_as_float(v.w & 0xffff0000u);
    return r;
}
__device__ __forceinline__ v4u pk8(f4 lo, f4 hi) {
    v4u r;
    r.x = rne(lo.x) | (rne(lo.y) << 16);
    r.y = rne(lo.z) | (rne(lo.w) << 16);
    r.z = rne(hi.x) | (rne(hi.y) << 16);
    r.w = rne(hi.z) | (rne(hi.w) << 16);
    return r;
}

// ---------------- init ----------------

__global__ void k_init(int* bcur1, int* off) {
    int i = blockIdx.x * blockDim.x + threadIdx.x;
    if (i < NB) bcur1[i] = i * BCAP;
    if (i == 0) off[N_NODES] = N_EDGES;   // sentinel: cnt[n] = off[n+1]-off[n]
}

// ---------------- bin: 391 buckets, packed (src<<8)|(dst&255) ----------------

__global__ __launch_bounds__(256) void k_bin1(const int* __restrict__ src,
                                              const int* __restrict__ dst,
                                              int* __restrict__ pairs1,
                                              int* __restrict__ bcur1) {
    __shared__ int cnt[NB];
    __shared__ int base[NB];
    const int tid = threadIdx.x;
    const int lo = blockIdx.x * BIN1_CHUNK;
    const int hi = min(lo + BIN1_CHUNK, N_EDGES);
    for (int j = tid; j < NB; j += 256) cnt[j] = 0;
    __syncthreads();
    for (int i = lo + tid; i < hi; i += 256) {
        int d = __builtin_nontemporal_load(dst + i);
        atomicAdd(&cnt[d >> 8], 1);
    }
    __syncthreads();
    for (int j = tid; j < NB; j += 256)
        if (cnt[j] > 0) base[j] = atomicAdd(&bcur1[j], cnt[j]);
    __syncthreads();
    for (int j = tid; j < NB; j += 256) cnt[j] = 0;
    __syncthreads();
    for (int i = lo + tid; i < hi; i += 256) {
        int d = __builtin_nontemporal_load(dst + i);
        int s = __builtin_nontemporal_load(src + i);
        int b = d >> 8;
        int r = atomicAdd(&cnt[b], 1);
        pairs1[base[b] + r] = (s << 8) | (d & 255);
    }
}

// ---------------- bucket-total exclusive scan (1 block, 512 thr) ------------

__global__ __launch_bounds__(512) void k_bucketscan(const int* __restrict__ bcur1,
                                                    int* __restrict__ bucketoff) {
    __shared__ int sm[512];
    const int tid = threadIdx.x;
    int v = (tid < NB) ? (bcur1[tid] - tid * BCAP) : 0;
    sm[tid] = v;
    __syncthreads();
    for (int st = 1; st < 512; st <<= 1) {
        int t = (tid >= st) ? sm[tid - st] : 0;
        __syncthreads();
        sm[tid] += t;
        __syncthreads();
    }
    if (tid < NB) bucketoff[tid] = sm[tid] - v;  // exclusive
}

// ---------------- per-bucket: count + scan + place + write + off/dinv -------

__global__ __launch_bounds__(256) void k_scatterXL(const int* __restrict__ pairs1,
                                                   const int* __restrict__ bcur1,
                                                   const int* __restrict__ bucketoff,
                                                   int* __restrict__ off,
                                                   float* __restrict__ dinv,
                                                   int* __restrict__ csr) {
    __shared__ int cnt[256];
    __shared__ int lcur[256];
    __shared__ int buf[BCAP];
    const int b = blockIdx.x;
    const int tid = threadIdx.x;
    const int base1 = b * BCAP;
    const int len = min(bcur1[b] - base1, BCAP);
    const int gbase = bucketoff[b];
    cnt[tid] = 0;
    __syncthreads();
    for (int i = tid; i < len; i += 256)
        atomicAdd(&cnt[pairs1[base1 + i] & 255], 1);
    __syncthreads();
    int v = cnt[tid];
    lcur[tid] = v;
    __syncthreads();
    for (int st = 1; st < 256; st <<= 1) {
        int t = (tid >= st) ? lcur[tid - st] : 0;
        __syncthreads();
        lcur[tid] += t;
        __syncthreads();
    }
    int excl = lcur[tid] - v;
    __syncthreads();
    lcur[tid] = excl;
    int node = b * 256 + tid;
    if (node < N_NODES) {
        off[node] = gbase + excl;
        dinv[node] = rsqrtf((float)(1 + v));
    }
    __syncthreads();
    for (int i = tid; i < len; i += 256) {
        int e = pairs1[base1 + i];
        int p = atomicAdd(&lcur[e & 255], 1);   // LDS atomic, block-local
        buf[p] = e >> 8;                        // src id
    }
    __syncthreads();
    for (int i = tid; i < len; i += 256)
        csr[gbase + i] = buf[i];                // fully coalesced
}

// ---------------- GEMM1: y1(bf16) = (x @ W1) * dinv[n] ----------------

#define G1_BS 256
#define G1_NODES 128
#define G1_KT 64
#define G1_STRIDE (G1_KT + 4)

__global__ __launch_bounds__(G1_BS) void k_gemm1(const float* __restrict__ x,
                                                 const float* __restrict__ W1,
                                                 const float* __restrict__ dinv,
                                                 unsigned short* __restrict__ y1) {
    __shared__ float xt[G1_NODES * G1_STRIDE];  // 34816 B
    __shared__ float wt[G1_KT * HID];           // 4096 B
    const int tid = threadIdx.x;
    const int nl = tid >> 2;   // node slot 0..63
    const int cg = tid & 3;    // channel group (4 ch each)
    const int node_base = blockIdx.x * G1_NODES;

    f4 acc0 = {0.f, 0.f, 0.f, 0.f};
    f4 acc1 = {0.f, 0.f, 0.f, 0.f};

    for (int kt = 0; kt < IN_CH; kt += G1_KT) {
        __syncthreads();
        for (int j = 0; j < 8; ++j) {
            int f = j * G1_BS + tid;
            int r = f >> 4;
            int c4 = f & 15;
            int gr = node_base + r;
            f4 v = {0.f, 0.f, 0.f, 0.f};
            if (gr < N_NODES)
                v = *(const f4*)(x + (size_t)gr * IN_CH + kt + c4 * 4);
            *(f4*)(xt + r * G1_STRIDE + c4 * 4) = v;
        }
        {
            int r = tid >> 2;
            int c4 = tid & 3;
            *(f4*)(wt + r * HID + c4 * 4) =
                *(const f4*)(W1 + (size_t)(kt + r) * HID + c4 * 4);
        }
        __syncthreads();

        for (int kk = 0; kk < G1_KT; kk += 4) {
            f4 x0 = *(const f4*)(xt + nl * G1_STRIDE + kk);
            f4 x1 = *(const f4*)(xt + (nl + 64) * G1_STRIDE + kk);
            f4 w0 = *(const f4*)(wt + (kk + 0) * HID + cg * 4);
            f4 w1 = *(const f4*)(wt + (kk + 1) * HID + cg * 4);
            f4 w2 = *(const f4*)(wt + (kk + 2) * HID + cg * 4);
            f4 w3 = *(const f4*)(wt + (kk + 3) * HID + cg * 4);
            acc0 += x0.x * w0; acc0 += x0.y * w1;
            acc0 += x0.z * w2; acc0 += x0.w * w3;
            acc1 += x1.x * w0; acc1 += x1.y * w1;
            acc1 += x1.z * w2; acc1 += x1.w * w3;
        }
    }

    int n0 = node_base + nl;
    int n1 = n0 + 64;
    if (n0 < N_NODES) {
        float dv = dinv[n0];
        __builtin_nontemporal_store(pk4(acc0 * dv),
            (v2u*)(y1 + (size_t)n0 * HID + cg * 4));
    }
    if (n1 < N_NODES) {
        float dv = dinv[n1];
        __builtin_nontemporal_store(pk4(acc1 * dv),
            (v2u*)(y1 + (size_t)n1 * HID + cg * 4));
    }
}

// ---------------- layer1: 2 threads/node, 16B bf16 gathers ----------------

__global__ __launch_bounds__(256) void k_layer1(const unsigned short* __restrict__ y1,
                                                const int* __restrict__ off,
                                                const int* __restrict__ csr,
                                                const float* __restrict__ b1,
                                                unsigned short* __restrict__ y2) {
    int t = blockIdx.x * blockDim.x + threadIdx.x;
    int n = t >> 1;
    int hf = (t & 1) * 8;   // this thread's 8 channels
    if (n >= N_NODES) return;
    int base = off[n];
    int cnt = off[n + 1] - base;
    f4 l0 = {0,0,0,0}, h0 = {0,0,0,0}, l1 = {0,0,0,0}, h1 = {0,0,0,0};
    f4 l2 = {0,0,0,0}, h2 = {0,0,0,0}, l3 = {0,0,0,0}, h3 = {0,0,0,0};
    int p = 0;
    for (; p + 4 <= cnt; p += 4) {
        int s0 = csr[base + p + 0];
        int s1 = csr[base + p + 1];
        int s2 = csr[base + p + 2];
        int s3 = csr[base + p + 3];
        v4u g0 = *(const v4u*)(y1 + (size_t)s0 * HID + hf);
        v4u g1 = *(const v4u*)(y1 + (size_t)s1 * HID + hf);
        v4u g2 = *(const v4u*)(y1 + (size_t)s2 * HID + hf);
        v4u g3 = *(const v4u*)(y1 + (size_t)s3 * HID + hf);
        l0 += up_lo(g0); h0 += up_hi(g0);
        l1 += up_lo(g1); h1 += up_hi(g1);
        l2 += up_lo(g2); h2 += up_hi(g2);
        l3 += up_lo(g3); h3 += up_hi(g3);
    }
    for (; p < cnt; ++p) {
        v4u g = *(const v4u*)(y1 + (size_t)csr[base + p] * HID + hf);
        l0 += up_lo(g); h0 += up_hi(g);
    }
    f4 alo = (l0 + l1) + (l2 + l3);
    f4 ahi = (h0 + h1) + (h2 + h3);
    float dv = rsqrtf((float)(cnt + 1));
    v4u gs = *(const v4u*)(y1 + (size_t)n * HID + hf);
    alo += up_lo(gs);
    ahi += up_hi(gs);
    f4 blo = ((const f4*)b1)[(t & 1) * 2 + 0];
    f4 bhi = ((const f4*)b1)[(t & 1) * 2 + 1];
    f4 rlo, rhi;
    rlo.x = fmaxf(dv * alo.x + blo.x, 0.f) * dv;
    rlo.y = fmaxf(dv * alo.y + blo.y, 0.f) * dv;
    rlo.z = fmaxf(dv * alo.z + blo.z, 0.f) * dv;
    rlo.w = fmaxf(dv * alo.w + blo.w, 0.f) * dv;
    rhi.x = fmaxf(dv * ahi.x + bhi.x, 0.f) * dv;
    rhi.y = fmaxf(dv * ahi.y + bhi.y, 0.f) * dv;
    rhi.z = fmaxf(dv * ahi.z + bhi.z, 0.f) * dv;
    rhi.w = fmaxf(dv * ahi.w + bhi.w, 0.f) * dv;
    __builtin_nontemporal_store(pk8(rlo, rhi), (v4u*)(y2 + (size_t)n * HID + hf));
}

// ---------------- layer2: 2 threads/node gathers + fused GEMM2 ----------------

__global__ __launch_bounds__(256) void k_layer2(const unsigned short* __restrict__ y2,
                                                const int* __restrict__ off,
                                                const int* __restrict__ csr,
                                                const float* __restrict__ W2,
                                                const float* __restrict__ b2,
                                                float* __restrict__ out) {
    __shared__ float w2[HID * OUT_CH];  // 4 KB
    __shared__ float bs[OUT_CH];
    int tid = threadIdx.x;
    for (int j = tid; j < HID * OUT_CH; j += 256) w2[j] = W2[j];
    if (tid < OUT_CH) bs[tid] = b2[tid];
    __syncthreads();

    int t = blockIdx.x * blockDim.x + tid;
    int n = t >> 1;
    int cg = t & 1;
    int hf = cg * 8;
    if (n >= N_NODES) return;
    int base = off[n];
    int cnt = off[n + 1] - base;
    f4 l0 = {0,0,0,0}, h0 = {0,0,0,0}, l1 = {0,0,0,0}, h1 = {0,0,0,0};
    f4 l2 = {0,0,0,0}, h2 = {0,0,0,0}, l3 = {0,0,0,0}, h3 = {0,0,0,0};
    int p = 0;
    for (; p + 4 <= cnt; p += 4) {
        int s0 = csr[base + p + 0];
        int s1 = csr[base + p + 1];
        int s2 = csr[base + p + 2];
        int s3 = csr[base + p + 3];
        v4u g0 = *(const v4u*)(y2 + (size_t)s0 * HID + hf);
        v4u g1 = *(const v4u*)(y2 + (size_t)s1 * HID + hf);
        v4u g2 = *(const v4u*)(y2 + (size_t)s2 * HID + hf);
        v4u g3 = *(const v4u*)(y2 + (size_t)s3 * HID + hf);
        l0 += up_lo(g0); h0 += up_hi(g0);
        l1 += up_lo(g1); h1 += up_hi(g1);
        l2 += up_lo(g2); h2 += up_hi(g2);
        l3 += up_lo(g3); h3 += up_hi(g3);
    }
    for (; p < cnt; ++p) {
        v4u g = *(const v4u*)(y2 + (size_t)csr[base + p] * HID + hf);
        l0 += up_lo(g); h0 += up_hi(g);
    }
    f4 alo = (l0 + l1) + (l2 + l3);
    f4 ahi = (h0 + h1) + (h2 + h3);
    float dv = rsqrtf((float)(cnt + 1));
    v4u gs = *(const v4u*)(y2 + (size_t)n * HID + hf);
    alo += up_lo(gs);
    ahi += up_hi(gs);
    // this thread's 8 z channels (hf..hf+7)
    float zown[8] = {dv * alo.x, dv * alo.y, dv * alo.z, dv * alo.w,
                     dv * ahi.x, dv * ahi.y, dv * ahi.z, dv * ahi.w};
    // exchange with partner lane (lane^1) to assemble z[16]
    float z[16];
#pragma unroll
    for (int j = 0; j < 8; ++j) {
        float zp = __shfl_xor(zown[j], 1, 64);
        z[hf + j] = zown[j];
        z[(8 - hf) + j] = zp;
    }
    // this thread computes 8 interleaved f4 chunks: channels (2j+cg)*4..+3
    f4 o[8];
#pragma unroll
    for (int j = 0; j < 8; ++j) o[j] = ((const f4*)bs)[j * 2 + cg];
#pragma unroll
    for (int cc = 0; cc < HID; ++cc) {
        const float* wr = w2 + cc * OUT_CH;
        float zz = z[cc];
#pragma unroll
        for (int j = 0; j < 8; ++j)
            o[j] += zz * *(const f4*)(wr + (j * 2 + cg) * 4);
    }
    float* orow = out + (size_t)n * OUT_CH;
#pragma unroll
    for (int j = 0; j < 8; ++j)
        __builtin_nontemporal_store(o[j], (f4*)(orow + (j * 2 + cg) * 4));
}

// ---------------- launch ----------------

extern "C" void kernel_launch(void* const* d_in, const int* in_sizes, int n_in,
                              void* d_out, int out_size, void* d_ws, size_t ws_size,
                              hipStream_t stream) {
    const float* x  = (const float*)d_in[0];
    const int*   ei = (const int*)d_in[1];
    const float* W1 = (const float*)d_in[2];
    const float* b1 = (const float*)d_in[3];
    const float* W2 = (const float*)d_in[4];
    const float* b2 = (const float*)d_in[5];
    float* out = (float*)d_out;

    const int* src = ei;            // edge_index[0]
    const int* dst = ei + N_EDGES;  // edge_index[1]

    char* w = (char*)d_ws;
    const size_t SN = 409600;  // per-N-array slot
    float* dinv      = (float*)(w);
    int*   off       = (int*)(w + SN);                  // 400004 B (sentinel)
    int*   bcur1     = (int*)(w + 2 * SN);              // 1564 B
    int*   bucketoff = (int*)(w + 2 * SN + 8192);       // 1564 B
    char*  regB      = w + 3 * SN;
    int*   pairs1    = (int*)regB;                      // 391*9472*4 = 14.8 MB
    int*   csr       = (int*)(regB + (size_t)NB * BCAP * 4);   // 12.8 MB
    char*  regC      = regB + (size_t)NB * BCAP * 4 + 12800000;
    unsigned short* y1 = (unsigned short*)regC;         // 3.2 MB
    unsigned short* y2 = (unsigned short*)(regC + 3200000);  // 3.2 MB
    // total ws use: ~35.2 MB

    k_init<<<(NB + 255) / 256, 256, 0, stream>>>(bcur1, off);
    k_bin1<<<BIN1_BLOCKS, 256, 0, stream>>>(src, dst, pairs1, bcur1);
    k_bucketscan<<<1, 512, 0, stream>>>(bcur1, bucketoff);
    k_scatterXL<<<NB, 256, 0, stream>>>(pairs1, bcur1, bucketoff, off, dinv, csr);
    k_gemm1<<<(N_NODES + G1_NODES - 1) / G1_NODES, G1_BS, 0, stream>>>(x, W1, dinv, y1);
    k_layer1<<<(N_NODES * 2 + 255) / 256, 256, 0, stream>>>(y1, off, csr, b1, y2);
    k_layer2<<<(N_NODES * 2 + 255) / 256, 256, 0, stream>>>(y2, off, csr, W2, b2, out);
}

// Round 13
// 205.762 us; speedup vs baseline: 1.0914x; 1.0914x over previous
//
#include <hip/hip_runtime.h>

#define N_NODES 100000
#define N_EDGES 3200000
#define IN_CH 512
#define HID 16
#define OUT_CH 64

// ---- hierarchical counting-sort geometry (R10-best config) ----
#define NB1 98
#define CAP1 34816
#define LEAF 64
#define CAP2 2560
#define NLEAF 1563                 // ceil(100000/64)
#define NLEAF_SLOTS (NB1 * 16)     // 1568 allocated slots
#define BIN1_CHUNK 4096
#define BIN1_BLOCKS ((N_EDGES + BIN1_CHUNK - 1) / BIN1_CHUNK)  // 782
#define BIN2_SPLIT 9
#define BIN2_CHUNK 3872            // 9*3872 >= CAP1

typedef float f4 __attribute__((ext_vector_type(4)));
typedef unsigned int v2u __attribute__((ext_vector_type(2)));

// bf16 pack/unpack (RNE)
__device__ __forceinline__ unsigned rne(float f) {
    unsigned u = __float_as_uint(f);
    return (u + 0x7fffu + ((u >> 16) & 1u)) >> 16;
}
__device__ __forceinline__ v2u pk4(f4 f) {
    v2u r;
    r.x = rne(f.x) | (rne(f.y) << 16);
    r.y = rne(f.z) | (rne(f.w) << 16);
    return r;
}
__device__ __forceinline__ f4 up4(v2u v) {
    f4 r;
    r.x = __uint_as_float(v.x << 16);
    r.y = __uint_as_float(v.x & 0xffff0000u);
    r.z = __uint_as_float(v.y << 16);
    r.w = __uint_as_float(v.y & 0xffff0000u);
    return r;
}

// ---------------- init ----------------

__global__ void k_init_bcur(int* bcur1, int* bcur2, int* off) {
    int i = blockIdx.x * blockDim.x + threadIdx.x;
    if (i < NB1) bcur1[i] = i * CAP1;
    if (i < NLEAF_SLOTS) bcur2[i] = i * CAP2;
    if (i == 0) off[N_NODES] = N_EDGES;   // sentinel: cnt[n] = off[n+1]-off[n]
}

// ---------------- L1 bin: 98 buckets, packed (src<<10)|local ----------------

__global__ __launch_bounds__(256) void k_bin1(const int* __restrict__ src,
                                              const int* __restrict__ dst,
                                              int* __restrict__ pairs1,
                                              int* __restrict__ bcur1) {
    __shared__ int cnt[NB1];
    __shared__ int base[NB1];
    const int tid = threadIdx.x;
    const int lo = blockIdx.x * BIN1_CHUNK;
    const int hi = min(lo + BIN1_CHUNK, N_EDGES);
    if (tid < NB1) cnt[tid] = 0;
    __syncthreads();
    for (int i = lo + tid; i < hi; i += 256) {
        int d = __builtin_nontemporal_load(dst + i);
        atomicAdd(&cnt[d >> 10], 1);
    }
    __syncthreads();
    if (tid < NB1 && cnt[tid] > 0) base[tid] = atomicAdd(&bcur1[tid], cnt[tid]);
    __syncthreads();
    if (tid < NB1) cnt[tid] = 0;
    __syncthreads();
    for (int i = lo + tid; i < hi; i += 256) {
        int d = __builtin_nontemporal_load(dst + i);
        int s = __builtin_nontemporal_load(src + i);
        int b = d >> 10;
        int r = atomicAdd(&cnt[b], 1);
        pairs1[base[b] + r] = (s << 10) | (d & 1023);
    }
}

// ---------------- L2 bin: 16 leaves within each bucket ----------------

__global__ __launch_bounds__(256) void k_bin2(const int* __restrict__ pairs1,
                                              const int* __restrict__ bcur1,
                                              int* __restrict__ pairs2,
                                              int* __restrict__ bcur2) {
    __shared__ int cnt[16];
    __shared__ int base[16];
    const int b = blockIdx.x / BIN2_SPLIT;
    const int s = blockIdx.x % BIN2_SPLIT;
    const int tid = threadIdx.x;
    const int len = bcur1[b] - b * CAP1;
    const int lo = b * CAP1 + min(s * BIN2_CHUNK, len);
    const int hi = b * CAP1 + min((s + 1) * BIN2_CHUNK, len);
    if (tid < 16) cnt[tid] = 0;
    __syncthreads();
    for (int i = lo + tid; i < hi; i += 256)
        atomicAdd(&cnt[(pairs1[i] & 1023) >> 6], 1);
    __syncthreads();
    if (tid < 16 && cnt[tid] > 0) base[tid] = atomicAdd(&bcur2[b * 16 + tid], cnt[tid]);
    __syncthreads();
    if (tid < 16) cnt[tid] = 0;
    __syncthreads();
    for (int i = lo + tid; i < hi; i += 256) {
        int e = pairs1[i];
        int l = (e & 1023) >> 6;
        int r = atomicAdd(&cnt[l], 1);
        pairs2[base[l] + r] = e;
    }
}

// ---------------- leaf-total exclusive scan (1 block) ----------------

__global__ __launch_bounds__(256) void k_leafscan(const int* __restrict__ bcur2,
                                                  int* __restrict__ leafoff) {
    __shared__ int sm[256];
    __shared__ int carry;
    const int tid = threadIdx.x;
    if (tid == 0) carry = 0;
    __syncthreads();
    for (int r = 0; r < (NLEAF_SLOTS + 255) / 256; ++r) {
        int idx = r * 256 + tid;
        int v = (idx < NLEAF_SLOTS) ? (bcur2[idx] - idx * CAP2) : 0;
        sm[tid] = v;
        __syncthreads();
        for (int st = 1; st < 256; st <<= 1) {
            int t = (tid >= st) ? sm[tid - st] : 0;
            __syncthreads();
            sm[tid] += t;
            __syncthreads();
        }
        if (idx < NLEAF_SLOTS) leafoff[idx] = carry + sm[tid] - v;  // exclusive
        int tot = sm[255];
        __syncthreads();
        if (tid == 0) carry += tot;
        __syncthreads();
    }
}

// ---------------- per-leaf: count + scan + scatter + off/dinv ---------------

__global__ __launch_bounds__(256) void k_scatter2(const int* __restrict__ pairs2,
                                                  const int* __restrict__ bcur2,
                                                  const int* __restrict__ leafoff,
                                                  int* __restrict__ off,
                                                  float* __restrict__ dinv,
                                                  int* __restrict__ csr) {
    __shared__ int cnt[LEAF];
    __shared__ int lcur[LEAF];
    __shared__ int buf[CAP2];
    const int leaf = blockIdx.x;
    const int tid = threadIdx.x;
    const int base2 = leaf * CAP2;
    const int len = min(bcur2[leaf] - base2, CAP2);
    const int obase = leafoff[leaf];
    if (tid < LEAF) cnt[tid] = 0;
    __syncthreads();
    for (int i = tid; i < len; i += 256)
        atomicAdd(&cnt[pairs2[base2 + i] & 63], 1);
    __syncthreads();
    if (tid < LEAF) {
        int v = cnt[tid];
        int s = v;
        for (int d = 1; d < LEAF; d <<= 1) {
            int t = __shfl_up(s, d, 64);
            if (tid >= d) s += t;
        }
        int excl = s - v;
        lcur[tid] = excl;
        int node = leaf * LEAF + tid;
        if (node < N_NODES) {
            off[node] = obase + excl;
            dinv[node] = rsqrtf((float)(1 + v));
        }
    }
    __syncthreads();
    for (int i = tid; i < len; i += 256) {
        int e = pairs2[base2 + i];
        int p = atomicAdd(&lcur[e & 63], 1);   // LDS atomic, block-local
        buf[p] = e >> 10;                      // src id
    }
    __syncthreads();
    for (int i = tid; i < len; i += 256)
        csr[obase + i] = buf[i];               // fully coalesced
}

// ---------------- GEMM1: y1(bf16) = (x @ W1) * dinv[n] ----------------

#define G1_BS 256
#define G1_NODES 128
#define G1_KT 64
#define G1_STRIDE (G1_KT + 4)

__global__ __launch_bounds__(G1_BS) void k_gemm1(const float* __restrict__ x,
                                                 const float* __restrict__ W1,
                                                 const float* __restrict__ dinv,
                                                 unsigned short* __restrict__ y1) {
    __shared__ float xt[G1_NODES * G1_STRIDE];  // 34816 B
    __shared__ float wt[G1_KT * HID];           // 4096 B
    const int tid = threadIdx.x;
    const int nl = tid >> 2;   // node slot 0..63
    const int cg = tid & 3;    // channel group (4 ch each)
    const int node_base = blockIdx.x * G1_NODES;

    f4 acc0 = {0.f, 0.f, 0.f, 0.f};
    f4 acc1 = {0.f, 0.f, 0.f, 0.f};

    for (int kt = 0; kt < IN_CH; kt += G1_KT) {
        __syncthreads();
        for (int j = 0; j < 8; ++j) {
            int f = j * G1_BS + tid;
            int r = f >> 4;
            int c4 = f & 15;
            int gr = node_base + r;
            f4 v = {0.f, 0.f, 0.f, 0.f};
            if (gr < N_NODES)
                v = *(const f4*)(x + (size_t)gr * IN_CH + kt + c4 * 4);
            *(f4*)(xt + r * G1_STRIDE + c4 * 4) = v;
        }
        {
            int r = tid >> 2;
            int c4 = tid & 3;
            *(f4*)(wt + r * HID + c4 * 4) =
                *(const f4*)(W1 + (size_t)(kt + r) * HID + c4 * 4);
        }
        __syncthreads();

        for (int kk = 0; kk < G1_KT; kk += 4) {
            f4 x0 = *(const f4*)(xt + nl * G1_STRIDE + kk);
            f4 x1 = *(const f4*)(xt + (nl + 64) * G1_STRIDE + kk);
            f4 w0 = *(const f4*)(wt + (kk + 0) * HID + cg * 4);
            f4 w1 = *(const f4*)(wt + (kk + 1) * HID + cg * 4);
            f4 w2 = *(const f4*)(wt + (kk + 2) * HID + cg * 4);
            f4 w3 = *(const f4*)(wt + (kk + 3) * HID + cg * 4);
            acc0 += x0.x * w0; acc0 += x0.y * w1;
            acc0 += x0.z * w2; acc0 += x0.w * w3;
            acc1 += x1.x * w0; acc1 += x1.y * w1;
            acc1 += x1.z * w2; acc1 += x1.w * w3;
        }
    }

    int n0 = node_base + nl;
    int n1 = n0 + 64;
    if (n0 < N_NODES) {
        float dv = dinv[n0];
        __builtin_nontemporal_store(pk4(acc0 * dv),
            (v2u*)(y1 + (size_t)n0 * HID + cg * 4));
    }
    if (n1 < N_NODES) {
        float dv = dinv[n1];
        __builtin_nontemporal_store(pk4(acc1 * dv),
            (v2u*)(y1 + (size_t)n1 * HID + cg * 4));
    }
}

// -------- layer1: 4 threads/node, 8B bf16 gathers, 8-deep MLP unroll --------

__global__ __launch_bounds__(256) void k_layer1(const unsigned short* __restrict__ y1,
                                                const int* __restrict__ off,
                                                const int* __restrict__ csr,
                                                const float* __restrict__ b1,
                                                unsigned short* __restrict__ y2) {
    int t = blockIdx.x * blockDim.x + threadIdx.x;
    int n = t >> 2;
    int cg = t & 3;
    if (n >= N_NODES) return;
    int base = off[n];
    int cnt = off[n + 1] - base;
    f4 a0 = {0,0,0,0}, a1 = {0,0,0,0}, a2 = {0,0,0,0}, a3 = {0,0,0,0};
    f4 a4 = {0,0,0,0}, a5 = {0,0,0,0}, a6 = {0,0,0,0}, a7 = {0,0,0,0};
    int p = 0;
    for (; p + 8 <= cnt; p += 8) {
        int s0 = csr[base + p + 0];
        int s1 = csr[base + p + 1];
        int s2 = csr[base + p + 2];
        int s3 = csr[base + p + 3];
        int s4 = csr[base + p + 4];
        int s5 = csr[base + p + 5];
        int s6 = csr[base + p + 6];
        int s7 = csr[base + p + 7];
        a0 += up4(*(const v2u*)(y1 + (size_t)s0 * HID + cg * 4));
        a1 += up4(*(const v2u*)(y1 + (size_t)s1 * HID + cg * 4));
        a2 += up4(*(const v2u*)(y1 + (size_t)s2 * HID + cg * 4));
        a3 += up4(*(const v2u*)(y1 + (size_t)s3 * HID + cg * 4));
        a4 += up4(*(const v2u*)(y1 + (size_t)s4 * HID + cg * 4));
        a5 += up4(*(const v2u*)(y1 + (size_t)s5 * HID + cg * 4));
        a6 += up4(*(const v2u*)(y1 + (size_t)s6 * HID + cg * 4));
        a7 += up4(*(const v2u*)(y1 + (size_t)s7 * HID + cg * 4));
    }
    for (; p < cnt; ++p)
        a0 += up4(*(const v2u*)(y1 + (size_t)csr[base + p] * HID + cg * 4));
    f4 acc = ((a0 + a1) + (a2 + a3)) + ((a4 + a5) + (a6 + a7));
    float dv = rsqrtf((float)(cnt + 1));
    f4 self = up4(*(const v2u*)(y1 + (size_t)n * HID + cg * 4));
    f4 b = ((const f4*)b1)[cg];
    f4 h;
    h.x = fmaxf(dv * (acc.x + self.x) + b.x, 0.f) * dv;
    h.y = fmaxf(dv * (acc.y + self.y) + b.y, 0.f) * dv;
    h.z = fmaxf(dv * (acc.z + self.z) + b.z, 0.f) * dv;
    h.w = fmaxf(dv * (acc.w + self.w) + b.w, 0.f) * dv;
    __builtin_nontemporal_store(pk4(h), (v2u*)(y2 + (size_t)n * HID + cg * 4));
}

// -------- layer2: 4 threads/node gathers (8-deep) + fused GEMM2 + bias ------

__global__ __launch_bounds__(256) void k_layer2(const unsigned short* __restrict__ y2,
                                                const int* __restrict__ off,
                                                const int* __restrict__ csr,
                                                const float* __restrict__ W2,
                                                const float* __restrict__ b2,
                                                float* __restrict__ out) {
    __shared__ float w2[HID * OUT_CH];  // 4 KB
    __shared__ float bs[OUT_CH];
    int tid = threadIdx.x;
    for (int j = tid; j < HID * OUT_CH; j += 256) w2[j] = W2[j];
    if (tid < OUT_CH) bs[tid] = b2[tid];
    __syncthreads();

    int t = blockIdx.x * blockDim.x + tid;
    int n = t >> 2;
    int cg = t & 3;
    if (n >= N_NODES) return;
    int base = off[n];
    int cnt = off[n + 1] - base;
    f4 a0 = {0,0,0,0}, a1 = {0,0,0,0}, a2 = {0,0,0,0}, a3 = {0,0,0,0};
    f4 a4 = {0,0,0,0}, a5 = {0,0,0,0}, a6 = {0,0,0,0}, a7 = {0,0,0,0};
    int p = 0;
    for (; p + 8 <= cnt; p += 8) {
        int s0 = csr[base + p + 0];
        int s1 = csr[base + p + 1];
        int s2 = csr[base + p + 2];
        int s3 = csr[base + p + 3];
        int s4 = csr[base + p + 4];
        int s5 = csr[base + p + 5];
        int s6 = csr[base + p + 6];
        int s7 = csr[base + p + 7];
        a0 += up4(*(const v2u*)(y2 + (size_t)s0 * HID + cg * 4));
        a1 += up4(*(const v2u*)(y2 + (size_t)s1 * HID + cg * 4));
        a2 += up4(*(const v2u*)(y2 + (size_t)s2 * HID + cg * 4));
        a3 += up4(*(const v2u*)(y2 + (size_t)s3 * HID + cg * 4));
        a4 += up4(*(const v2u*)(y2 + (size_t)s4 * HID + cg * 4));
        a5 += up4(*(const v2u*)(y2 + (size_t)s5 * HID + cg * 4));
        a6 += up4(*(const v2u*)(y2 + (size_t)s6 * HID + cg * 4));
        a7 += up4(*(const v2u*)(y2 + (size_t)s7 * HID + cg * 4));
    }
    for (; p < cnt; ++p)
        a0 += up4(*(const v2u*)(y2 + (size_t)csr[base + p] * HID + cg * 4));
    f4 acc = ((a0 + a1) + (a2 + a3)) + ((a4 + a5) + (a6 + a7));
    float dv = rsqrtf((float)(cnt + 1));
    f4 self = up4(*(const v2u*)(y2 + (size_t)n * HID + cg * 4));
    f4 z4 = {dv * (acc.x + self.x), dv * (acc.y + self.y),
             dv * (acc.z + self.z), dv * (acc.w + self.w)};

    // exchange z across the 4 lanes of this node
    int lane = tid & 63;
    int lbase = lane & ~3;
    float z[16];
#pragma unroll
    for (int j = 0; j < 4; ++j) {
        z[j * 4 + 0] = __shfl(z4.x, lbase + j, 64);
        z[j * 4 + 1] = __shfl(z4.y, lbase + j, 64);
        z[j * 4 + 2] = __shfl(z4.z, lbase + j, 64);
        z[j * 4 + 3] = __shfl(z4.w, lbase + j, 64);
    }

    // this thread computes out channels cg*16 .. cg*16+15
    f4 o0 = ((const f4*)bs)[cg * 4 + 0];
    f4 o1 = ((const f4*)bs)[cg * 4 + 1];
    f4 o2 = ((const f4*)bs)[cg * 4 + 2];
    f4 o3 = ((const f4*)bs)[cg * 4 + 3];
#pragma unroll
    for (int cc = 0; cc < HID; ++cc) {
        const float* wr = w2 + cc * OUT_CH + cg * 16;
        float zz = z[cc];
        o0 += zz * *(const f4*)(wr + 0);
        o1 += zz * *(const f4*)(wr + 4);
        o2 += zz * *(const f4*)(wr + 8);
        o3 += zz * *(const f4*)(wr + 12);
    }
    float* orow = out + (size_t)n * OUT_CH + cg * 16;
    __builtin_nontemporal_store(o0, (f4*)(orow + 0));
    __builtin_nontemporal_store(o1, (f4*)(orow + 4));
    __builtin_nontemporal_store(o2, (f4*)(orow + 8));
    __builtin_nontemporal_store(o3, (f4*)(orow + 12));
}

// ---------------- launch ----------------

extern "C" void kernel_launch(void* const* d_in, const int* in_sizes, int n_in,
                              void* d_out, int out_size, void* d_ws, size_t ws_size,
                              hipStream_t stream) {
    const float* x  = (const float*)d_in[0];
    const int*   ei = (const int*)d_in[1];
    const float* W1 = (const float*)d_in[2];
    const float* b1 = (const float*)d_in[3];
    const float* W2 = (const float*)d_in[4];
    const float* b2 = (const float*)d_in[5];
    float* out = (float*)d_out;

    const int* src = ei;            // edge_index[0]
    const int* dst = ei + N_EDGES;  // edge_index[1]

    char* w = (char*)d_ws;
    const size_t SN = 409600;  // per-N-array slot
    float* dinv     = (float*)(w);
    int*   off      = (int*)(w + SN);                   // 400004 B (sentinel)
    int*   bcur1    = (int*)(w + 2 * SN);
    int*   bcur2    = (int*)(w + 2 * SN + 8192);
    int*   leafoff  = (int*)(w + 2 * SN + 16384);
    // regB: pairs1 (13.65 MB) during binning, then csr (12.8 MB)
    char*  regB     = w + 3 * SN;
    int*   pairs1   = (int*)regB;
    int*   csr      = (int*)regB;
    // regC: pairs2 (16.06 MB) during sort, then bf16 {y1, y2} (3.2 MB each)
    char*  regC     = regB + (size_t)NB1 * CAP1 * 4;
    int*   pairs2   = (int*)regC;
    unsigned short* y1 = (unsigned short*)regC;
    unsigned short* y2 = (unsigned short*)(regC + 3200000);
    // total ws use: ~31 MB

    k_init_bcur<<<(NLEAF_SLOTS + 255) / 256, 256, 0, stream>>>(bcur1, bcur2, off);
    k_bin1<<<BIN1_BLOCKS, 256, 0, stream>>>(src, dst, pairs1, bcur1);
    k_bin2<<<NB1 * BIN2_SPLIT, 256, 0, stream>>>(pairs1, bcur1, pairs2, bcur2);
    k_leafscan<<<1, 256, 0, stream>>>(bcur2, leafoff);
    k_scatter2<<<NLEAF, 256, 0, stream>>>(pairs2, bcur2, leafoff, off, dinv, csr);
    k_gemm1<<<(N_NODES + G1_NODES - 1) / G1_NODES, G1_BS, 0, stream>>>(x, W1, dinv, y1);
    k_layer1<<<(N_NODES * 4 + 255) / 256, 256, 0, stream>>>(y1, off, csr, b1, y2);
    k_layer2<<<(N_NODES * 4 + 255) / 256, 256, 0, stream>>>(y2, off, csr, W2, b2, out);
}